// Round 1
// baseline (240.067 us; speedup 1.0000x reference)
//
#include <hip/hip_runtime.h>
#include <hip/hip_bf16.h>

#define B_   64
#define S_   2048
#define H_   256
#define H3_  768
#define K_   512            // 2H (static+dynamic)
#define MT   64             // M tile (positions per workgroup)

typedef __attribute__((ext_vector_type(8))) short  bf16x8;
typedef __attribute__((ext_vector_type(4))) float  f32x4;

__device__ __forceinline__ ushort f2bf(float f) {
    __hip_bfloat16 h = __float2bfloat16(f);
    return *reinterpret_cast<ushort*>(&h);
}

__device__ __forceinline__ float fast_tanh(float x) {
    // tanh(x) = 1 - 2/(exp(2x)+1); saturates correctly at +-inf
    float e = __expf(2.0f * x);
    return 1.0f - 2.0f / (e + 1.0f);
}

// ---------------- kernel 1: pack W[:, 0:512] to bf16, row-major [768 x 512]
__global__ void pack_w(const float* __restrict__ W, short* __restrict__ wbf) {
    int idx = blockIdx.x * 256 + threadIdx.x;          // over 768*512
    if (idx >= H3_ * K_) return;
    int o = idx >> 9;            // /512
    int k = idx & 511;
    wbf[idx] = (short)f2bf(W[o * H3_ + k]);
}

// ---------------- kernel 2: bias[b,o] = sum_k W[o,512+k] * dec[b,k]  (fp32)
__global__ void bias_k(const float* __restrict__ W, const float* __restrict__ dec,
                       float* __restrict__ bias) {
    int idx = blockIdx.x * 256 + threadIdx.x;          // over 64*768
    if (idx >= B_ * H3_) return;
    int b = idx / H3_;
    int o = idx - b * H3_;
    const float4* wr = (const float4*)(W + (size_t)o * H3_ + 2 * H_);
    const float4* dv = (const float4*)(dec + (size_t)b * H_);
    float s = 0.f;
#pragma unroll 8
    for (int k = 0; k < H_ / 4; ++k) {
        float4 a = wr[k], d = dv[k];
        s += a.x * d.x + a.y * d.y + a.z * d.z + a.w * d.w;
    }
    bias[idx] = s;
}

// ---------------- kernel 3: fused score GEMM
// scores[pos] = sum_o v[o] * tanh( sum_k X[pos,k]*W[o,k] + bias[b,o] )
// X[pos, 0:256] = static[pos], X[pos, 256:512] = dynamic[pos]
__global__ __launch_bounds__(256, 2)
void score_k(const float* __restrict__ stat, const float* __restrict__ dyn,
             const short* __restrict__ wbf, const float* __restrict__ bias,
             const float* __restrict__ v, float* __restrict__ scores) {
    __shared__ short aT[MT * K_];            // 64 KB, XOR-swizzled
    __shared__ float sred[4][MT];

    const int tid  = threadIdx.x;
    const int pos0 = blockIdx.x * MT;
    const int bidx = pos0 >> 11;             // /2048 ; tile never crosses b

    // ---- stage A: 64 rows x 512 cols bf16; float4 loads, convert, ds_write_b64
    // 8192 float4 elements total -> 32 iterations of 256 threads
#pragma unroll 4
    for (int it = 0; it < 32; ++it) {
        int lin = it * 256 + tid;
        int row = lin >> 7;                  // 128 float4 per row
        int c4  = lin & 127;
        int k   = c4 * 4;
        const float* src = (k < 256)
            ? (stat + (size_t)(pos0 + row) * H_ + k)
            : (dyn  + (size_t)(pos0 + row) * H_ + (k - 256));
        float4 f = *(const float4*)src;
        uint lo = (uint)f2bf(f.x) | ((uint)f2bf(f.y) << 16);
        uint hi = (uint)f2bf(f.z) | ((uint)f2bf(f.w) << 16);
        int off = row * (K_ * 2) + k * 2;
        off ^= (row & 7) << 4;               // bank-conflict swizzle
        *(uint2*)((char*)aT + off) = make_uint2(lo, hi);
    }
    __syncthreads();

    const int wave = tid >> 6;
    const int lane = tid & 63;
    const int lr = lane & 15;                // A: row-in-16 ; B/C: col-in-16
    const int lg = lane >> 4;                // k-group (8 elems each)

    float sacc[4][4];
#pragma unroll
    for (int mi = 0; mi < 4; ++mi)
#pragma unroll
        for (int j = 0; j < 4; ++j) sacc[mi][j] = 0.f;

    // 3 passes x (4 waves x 64 cols) = 768 cols
    for (int pass = 0; pass < 3; ++pass) {
        const int obase = pass * 256 + wave * 64;      // this wave's 64 cols
        f32x4 acc[4][4];                               // [mi][ni]
#pragma unroll
        for (int mi = 0; mi < 4; ++mi)
#pragma unroll
            for (int ni = 0; ni < 4; ++ni) acc[mi][ni] = (f32x4)0.f;

#pragma unroll 4
        for (int ks = 0; ks < 16; ++ks) {
            const int kb = ks * 32 + lg * 8;
            bf16x8 bfr[4];
#pragma unroll
            for (int ni = 0; ni < 4; ++ni) {
                int o = obase + ni * 16 + lr;
                bfr[ni] = *(const bf16x8*)(wbf + (size_t)o * K_ + kb);
            }
            bf16x8 afr[4];
#pragma unroll
            for (int mi = 0; mi < 4; ++mi) {
                int row = mi * 16 + lr;
                int off = row * (K_ * 2) + kb * 2;
                off ^= (row & 7) << 4;
                afr[mi] = *(const bf16x8*)((const char*)aT + off);
            }
#pragma unroll
            for (int mi = 0; mi < 4; ++mi)
#pragma unroll
                for (int ni = 0; ni < 4; ++ni)
                    acc[mi][ni] = __builtin_amdgcn_mfma_f32_16x16x32_bf16(
                        afr[mi], bfr[ni], acc[mi][ni], 0, 0, 0);
        }

        // epilogue: h += bias; sacc += v*tanh(h)
#pragma unroll
        for (int ni = 0; ni < 4; ++ni) {
            int o = obase + ni * 16 + lr;
            float bv = bias[bidx * H3_ + o];
            float vv = v[o];
#pragma unroll
            for (int mi = 0; mi < 4; ++mi)
#pragma unroll
                for (int j = 0; j < 4; ++j)
                    sacc[mi][j] += vv * fast_tanh(acc[mi][ni][j] + bv);
        }
    }

    // reduce over the 16 column-lanes (lr); rows live at (lg*4+j) per mi
#pragma unroll
    for (int mi = 0; mi < 4; ++mi)
#pragma unroll
        for (int j = 0; j < 4; ++j) {
            float x = sacc[mi][j];
            x += __shfl_xor(x, 1);
            x += __shfl_xor(x, 2);
            x += __shfl_xor(x, 4);
            x += __shfl_xor(x, 8);
            sacc[mi][j] = x;
        }
    if (lr == 0) {
#pragma unroll
        for (int mi = 0; mi < 4; ++mi)
#pragma unroll
            for (int j = 0; j < 4; ++j)
                sred[wave][mi * 16 + lg * 4 + j] = sacc[mi][j];
    }
    __syncthreads();
    if (tid < MT) {
        float s = sred[0][tid] + sred[1][tid] + sred[2][tid] + sred[3][tid];
        scores[pos0 + tid] = s;
    }
}

// ---------------- kernel 4: softmax over S=2048 per b, in place on d_out
__global__ void softmax_k(float* __restrict__ out) {
    const int b = blockIdx.x;
    float* row = out + (size_t)b * S_;
    const int tid  = threadIdx.x;          // 256
    const int wave = tid >> 6;
    const int lane = tid & 63;

    float vals[8];
    float m = -1e30f;
#pragma unroll
    for (int i = 0; i < 8; ++i) {
        vals[i] = row[tid + i * 256];
        m = fmaxf(m, vals[i]);
    }
#pragma unroll
    for (int off = 32; off >= 1; off >>= 1) m = fmaxf(m, __shfl_xor(m, off));
    __shared__ float redm[4];
    __shared__ float reds[4];
    if (lane == 0) redm[wave] = m;
    __syncthreads();
    m = fmaxf(fmaxf(redm[0], redm[1]), fmaxf(redm[2], redm[3]));

    float s = 0.f;
#pragma unroll
    for (int i = 0; i < 8; ++i) {
        vals[i] = __expf(vals[i] - m);
        s += vals[i];
    }
#pragma unroll
    for (int off = 32; off >= 1; off >>= 1) s += __shfl_xor(s, off);
    if (lane == 0) reds[wave] = s;
    __syncthreads();
    s = reds[0] + reds[1] + reds[2] + reds[3];
    float inv = 1.0f / s;
#pragma unroll
    for (int i = 0; i < 8; ++i) row[tid + i * 256] = vals[i] * inv;
}

extern "C" void kernel_launch(void* const* d_in, const int* in_sizes, int n_in,
                              void* d_out, int out_size, void* d_ws, size_t ws_size,
                              hipStream_t stream) {
    const float* stat = (const float*)d_in[0];   // [64,2048,256]
    const float* dyn  = (const float*)d_in[1];   // [64,2048,256]
    const float* dec  = (const float*)d_in[2];   // [64,256]
    const float* v    = (const float*)d_in[3];   // [1,768]
    const float* W    = (const float*)d_in[4];   // [768,768]
    float* out = (float*)d_out;                  // [64,2048]

    short* wbf  = (short*)d_ws;                               // 768*512*2 = 786432 B
    float* bias = (float*)((char*)d_ws + (size_t)H3_ * K_ * 2); // 64*768*4 B

    pack_w <<<(H3_ * K_ + 255) / 256, 256, 0, stream>>>(W, wbf);
    bias_k <<<(B_ * H3_ + 255) / 256, 256, 0, stream>>>(W, dec, bias);
    score_k<<<(B_ * S_) / MT, 256, 0, stream>>>(stat, dyn, wbf, bias, v, out);
    softmax_k<<<B_, 256, 0, stream>>>(out);
}

// Round 2
// 162.920 us; speedup vs baseline: 1.4735x; 1.4735x over previous
//
#include <hip/hip_runtime.h>
#include <hip/hip_bf16.h>

#define B_   64
#define S_   2048
#define H_   256
#define H3_  768
#define K_   512            // 2H (static+dynamic)
#define MT   64             // M tile (positions per workgroup)

typedef __attribute__((ext_vector_type(8))) short  bf16x8;
typedef __attribute__((ext_vector_type(4))) float  f32x4;

__device__ __forceinline__ ushort f2bf(float f) {
    __hip_bfloat16 h = __float2bfloat16(f);
    return *reinterpret_cast<ushort*>(&h);
}

__device__ __forceinline__ float fast_tanh(float x) {
    float e = __expf(2.0f * x);
    return 1.0f - 2.0f / (e + 1.0f);
}

// ---------------- kernel 1: pack W[:, 0:512] to bf16 in FRAGMENT order.
// Layout: [ot(48)][ks(16)][lane(64)][j(8)]
//   o = ot*16 + (lane&15), k = ks*32 + (lane>>4)*8 + j
// so score_k's B-fragment load is one coalesced 1KB/wave dwordx4.
__global__ void pack_w(const float* __restrict__ W, short* __restrict__ wpk) {
    int t = blockIdx.x * 256 + threadIdx.x;       // over 48*16*64
    if (t >= 48 * 16 * 64) return;
    int lane = t & 63;
    int ks   = (t >> 6) & 15;
    int ot   = t >> 10;
    int o  = ot * 16 + (lane & 15);
    int kb = ks * 32 + (lane >> 4) * 8;
    const float* src = W + (size_t)o * H3_ + kb;
    float4 a = ((const float4*)src)[0];
    float4 b = ((const float4*)src)[1];
    union { bf16x8 v; uint4 u; } pk;
    pk.u.x = (uint)f2bf(a.x) | ((uint)f2bf(a.y) << 16);
    pk.u.y = (uint)f2bf(a.z) | ((uint)f2bf(a.w) << 16);
    pk.u.z = (uint)f2bf(b.x) | ((uint)f2bf(b.y) << 16);
    pk.u.w = (uint)f2bf(b.z) | ((uint)f2bf(b.w) << 16);
    *(bf16x8*)(wpk + (size_t)t * 8) = pk.v;
}

// ---------------- kernel 2: bias[b,o] = sum_k W[o,512+k] * dec[b,k]  (fp32)
__global__ void bias_k(const float* __restrict__ W, const float* __restrict__ dec,
                       float* __restrict__ bias) {
    int idx = blockIdx.x * 256 + threadIdx.x;     // over 64*768
    if (idx >= B_ * H3_) return;
    int b = idx / H3_;
    int o = idx - b * H3_;
    const float4* wr = (const float4*)(W + (size_t)o * H3_ + 2 * H_);
    const float4* dv = (const float4*)(dec + (size_t)b * H_);
    float s = 0.f;
#pragma unroll 8
    for (int k = 0; k < H_ / 4; ++k) {
        float4 a = wr[k], d = dv[k];
        s += a.x * d.x + a.y * d.y + a.z * d.z + a.w * d.w;
    }
    bias[idx] = s;
}

// ---------------- kernel 3: fused score GEMM
// scores[pos] = sum_o v[o] * tanh( sum_k X[pos,k]*W[o,k] + bias[b,o] )
__global__ __launch_bounds__(256, 2)
void score_k(const float* __restrict__ stat, const float* __restrict__ dyn,
             const short* __restrict__ wpk, const float* __restrict__ bias,
             const float* __restrict__ v, float* __restrict__ scores) {
    __shared__ short aT[MT * K_];            // 64 KB, XOR-swizzled
    __shared__ float sred[4][MT];

    const int tid  = threadIdx.x;
    const int pos0 = blockIdx.x * MT;
    const int bidx = pos0 >> 11;             // /2048 ; tile never crosses b

    // ---- stage A: 64 rows x 512 cols bf16.
    // Unit = 8 floats (two float4 loads -> one 16B ds_write).
    // 64 rows x 64 units = 4096 units; 16 units/thread in 2 batches of 8
    // (16 global loads in flight per lane per batch -> ~32KB/CU in flight).
#pragma unroll
    for (int bat = 0; bat < 2; ++bat) {
        float4 f0[8], f1[8];
#pragma unroll
        for (int u = 0; u < 8; ++u) {
            int lin = (bat * 8 + u) * 256 + tid;
            int row = lin >> 6;              // 64 units per row
            int k   = (lin & 63) * 8;
            const float* src = (k < 256)
                ? (stat + (size_t)(pos0 + row) * H_ + k)
                : (dyn  + (size_t)(pos0 + row) * H_ + (k - 256));
            f0[u] = ((const float4*)src)[0];
            f1[u] = ((const float4*)src)[1];
        }
#pragma unroll
        for (int u = 0; u < 8; ++u) {
            int lin = (bat * 8 + u) * 256 + tid;
            int row = lin >> 6;
            int k   = (lin & 63) * 8;
            uint4 pk;
            pk.x = (uint)f2bf(f0[u].x) | ((uint)f2bf(f0[u].y) << 16);
            pk.y = (uint)f2bf(f0[u].z) | ((uint)f2bf(f0[u].w) << 16);
            pk.z = (uint)f2bf(f1[u].x) | ((uint)f2bf(f1[u].y) << 16);
            pk.w = (uint)f2bf(f1[u].z) | ((uint)f2bf(f1[u].w) << 16);
            int off = row * (K_ * 2) + k * 2;
            off ^= (row & 7) << 4;           // bank-conflict swizzle
            *(uint4*)((char*)aT + off) = pk;
        }
    }
    __syncthreads();

    const int wave = tid >> 6;
    const int lane = tid & 63;
    const int lr = lane & 15;                // A: row-in-16 ; B/C: col-in-16
    const int lg = lane >> 4;                // k-group (8 elems each)

    float sacc[4][4];
#pragma unroll
    for (int mi = 0; mi < 4; ++mi)
#pragma unroll
        for (int j = 0; j < 4; ++j) sacc[mi][j] = 0.f;

    // 3 passes x (4 waves x 64 cols) = 768 cols
    for (int pass = 0; pass < 3; ++pass) {
        const int obase = pass * 256 + wave * 64;      // this wave's 64 cols
        f32x4 acc[4][4];                               // [mi][ni]
#pragma unroll
        for (int mi = 0; mi < 4; ++mi)
#pragma unroll
            for (int ni = 0; ni < 4; ++ni) acc[mi][ni] = (f32x4)0.f;

#pragma unroll 4
        for (int ks = 0; ks < 16; ++ks) {
            bf16x8 bfr[4];
#pragma unroll
            for (int ni = 0; ni < 4; ++ni) {
                int ot = pass * 16 + wave * 4 + ni;    // o-tile index
                bfr[ni] = *(const bf16x8*)(wpk +
                    ((size_t)(ot * 16 + ks) * 64 + lane) * 8);
            }
            const int kb = ks * 32 + lg * 8;
            bf16x8 afr[4];
#pragma unroll
            for (int mi = 0; mi < 4; ++mi) {
                int row = mi * 16 + lr;
                int off = row * (K_ * 2) + kb * 2;
                off ^= (row & 7) << 4;
                afr[mi] = *(const bf16x8*)((const char*)aT + off);
            }
#pragma unroll
            for (int mi = 0; mi < 4; ++mi)
#pragma unroll
                for (int ni = 0; ni < 4; ++ni)
                    acc[mi][ni] = __builtin_amdgcn_mfma_f32_16x16x32_bf16(
                        afr[mi], bfr[ni], acc[mi][ni], 0, 0, 0);
        }

        // epilogue: h += bias; sacc += v*tanh(h)
#pragma unroll
        for (int ni = 0; ni < 4; ++ni) {
            int o = obase + ni * 16 + lr;
            float bv = bias[bidx * H3_ + o];
            float vv = v[o];
#pragma unroll
            for (int mi = 0; mi < 4; ++mi)
#pragma unroll
                for (int j = 0; j < 4; ++j)
                    sacc[mi][j] += vv * fast_tanh(acc[mi][ni][j] + bv);
        }
    }

    // reduce over the 16 column-lanes (lr); rows live at (lg*4+j) per mi
#pragma unroll
    for (int mi = 0; mi < 4; ++mi)
#pragma unroll
        for (int j = 0; j < 4; ++j) {
            float x = sacc[mi][j];
            x += __shfl_xor(x, 1);
            x += __shfl_xor(x, 2);
            x += __shfl_xor(x, 4);
            x += __shfl_xor(x, 8);
            sacc[mi][j] = x;
        }
    if (lr == 0) {
#pragma unroll
        for (int mi = 0; mi < 4; ++mi)
#pragma unroll
            for (int j = 0; j < 4; ++j)
                sred[wave][mi * 16 + lg * 4 + j] = sacc[mi][j];
    }
    __syncthreads();
    if (tid < MT) {
        float s = sred[0][tid] + sred[1][tid] + sred[2][tid] + sred[3][tid];
        scores[pos0 + tid] = s;
    }
}

// ---------------- kernel 4: softmax over S=2048 per b, in place on d_out
__global__ void softmax_k(float* __restrict__ out) {
    const int b = blockIdx.x;
    float* row = out + (size_t)b * S_;
    const int tid  = threadIdx.x;          // 256
    const int wave = tid >> 6;
    const int lane = tid & 63;

    float vals[8];
    float m = -1e30f;
#pragma unroll
    for (int i = 0; i < 8; ++i) {
        vals[i] = row[tid + i * 256];
        m = fmaxf(m, vals[i]);
    }
#pragma unroll
    for (int off = 32; off >= 1; off >>= 1) m = fmaxf(m, __shfl_xor(m, off));
    __shared__ float redm[4];
    __shared__ float reds[4];
    if (lane == 0) redm[wave] = m;
    __syncthreads();
    m = fmaxf(fmaxf(redm[0], redm[1]), fmaxf(redm[2], redm[3]));

    float s = 0.f;
#pragma unroll
    for (int i = 0; i < 8; ++i) {
        vals[i] = __expf(vals[i] - m);
        s += vals[i];
    }
#pragma unroll
    for (int off = 32; off >= 1; off >>= 1) s += __shfl_xor(s, off);
    if (lane == 0) reds[wave] = s;
    __syncthreads();
    s = reds[0] + reds[1] + reds[2] + reds[3];
    float inv = 1.0f / s;
#pragma unroll
    for (int i = 0; i < 8; ++i) row[tid + i * 256] = vals[i] * inv;
}

extern "C" void kernel_launch(void* const* d_in, const int* in_sizes, int n_in,
                              void* d_out, int out_size, void* d_ws, size_t ws_size,
                              hipStream_t stream) {
    const float* stat = (const float*)d_in[0];   // [64,2048,256]
    const float* dyn  = (const float*)d_in[1];   // [64,2048,256]
    const float* dec  = (const float*)d_in[2];   // [64,256]
    const float* v    = (const float*)d_in[3];   // [1,768]
    const float* W    = (const float*)d_in[4];   // [768,768]
    float* out = (float*)d_out;                  // [64,2048]

    short* wpk  = (short*)d_ws;                                 // 786432 B
    float* bias = (float*)((char*)d_ws + (size_t)H3_ * K_ * 2); // 196608 B

    pack_w <<<(48 * 16 * 64 + 255) / 256, 256, 0, stream>>>(W, wpk);
    bias_k <<<(B_ * H3_ + 255) / 256, 256, 0, stream>>>(W, dec, bias);
    score_k<<<(B_ * S_) / MT, 256, 0, stream>>>(stat, dyn, wpk, bias, v, out);
    softmax_k<<<B_, 256, 0, stream>>>(out);
}